// Round 16
// baseline (378.633 us; speedup 1.0000x reference)
//
#include <hip/hip_runtime.h>
#include <stdint.h>

// Problem constants (B=4, T=2048, C=1024, H=16, HD=64)
#define TSEQ 2048
#define CDIM 1024
#define NHEAD 16
#define HDIM 64
#define NROWS 8192  // B*T

typedef __bf16 bf16x8 __attribute__((ext_vector_type(8)));
typedef float f32x4 __attribute__((ext_vector_type(4)));
typedef float f32x16 __attribute__((ext_vector_type(16)));

__device__ __forceinline__ unsigned short f2bf(float f) {
  unsigned u = __builtin_bit_cast(unsigned, f);
  u = u + 0x7fffu + ((u >> 16) & 1u);
  return (unsigned short)(u >> 16);
}

__device__ __forceinline__ float bf2f(unsigned short u) {
  return __builtin_bit_cast(float, (unsigned)u << 16);
}

__device__ __forceinline__ unsigned cvt_pk_bf16(float a, float b) {
  unsigned r;
  asm("v_cvt_pk_bf16_f32 %0, %1, %2" : "=v"(r) : "v"(a), "v"(b));
  return r;
}

__device__ __forceinline__ float gelu_f(float x) {
  float x3 = x * x * x;
  float z = 0.7978845608028654f * (x + 0.044715f * x3);
  float e = __expf(2.f * z);
  float t = 1.f - 2.f / (e + 1.f);
  return 0.5f * x * (1.f + t);
}

// async 16B global->LDS (lds dest must be wave-uniform; HW adds lane*16)
__device__ __forceinline__ void ldg_lds16(void* lds, const void* gsrc) {
  __builtin_amdgcn_global_load_lds(
      (__attribute__((address_space(1))) unsigned int*)(uintptr_t)gsrc,
      (__attribute__((address_space(3))) unsigned int*)lds,
      16, 0, 0);
}

// ---------------- weight transpose+convert: W fp32 [K][N] -> Wt bf16 [N][K]
__global__ __launch_bounds__(256) void k_wtrans(const float* __restrict__ W,
                                                unsigned short* __restrict__ Wt,
                                                int K, int N) {
  __shared__ unsigned short tl[32][40];
  int n0 = blockIdx.x * 32, k0 = blockIdx.y * 32;
  int tid = threadIdx.x;
  int r = tid >> 3, c4 = (tid & 7) * 4;
  float4 v = *(const float4*)(W + (size_t)(k0 + r) * N + n0 + c4);
  ushort4 o;
  o.x = f2bf(v.x); o.y = f2bf(v.y); o.z = f2bf(v.z); o.w = f2bf(v.w);
  *(ushort4*)&tl[r][c4] = o;
  __syncthreads();
  int n = tid >> 3, k4 = (tid & 7) * 4;
  ushort4 w;
  w.x = tl[k4 + 0][n]; w.y = tl[k4 + 1][n]; w.z = tl[k4 + 2][n]; w.w = tl[k4 + 3][n];
  *(ushort4*)(Wt + (size_t)(n0 + n) * K + k0 + k4) = w;
}

// ---------------- layernorm: IN 0: fp32 input; IN 1: bf16 input -> bf16 out
template <int IN>
__global__ __launch_bounds__(256) void k_ln(const void* __restrict__ xin,
                                            const float* __restrict__ w,
                                            const float* __restrict__ b,
                                            unsigned short* __restrict__ out) {
  int row = blockIdx.x;
  int tid = threadIdx.x;
  float4 v;
  if (IN == 0) {
    v = *(const float4*)((const float*)xin + (size_t)row * CDIM + tid * 4);
  } else {
    ushort4 u = *(const ushort4*)((const unsigned short*)xin + (size_t)row * CDIM + tid * 4);
    v.x = bf2f(u.x); v.y = bf2f(u.y); v.z = bf2f(u.z); v.w = bf2f(u.w);
  }
  float s = v.x + v.y + v.z + v.w;
  float s2 = v.x * v.x + v.y * v.y + v.z * v.z + v.w * v.w;
#pragma unroll
  for (int off = 32; off; off >>= 1) {
    s += __shfl_xor(s, off);
    s2 += __shfl_xor(s2, off);
  }
  __shared__ float rbuf[8];
  int wv = tid >> 6, lane = tid & 63;
  if (lane == 0) { rbuf[wv] = s; rbuf[4 + wv] = s2; }
  __syncthreads();
  float S1 = rbuf[0] + rbuf[1] + rbuf[2] + rbuf[3];
  float S2 = rbuf[4] + rbuf[5] + rbuf[6] + rbuf[7];
  float mean = S1 * (1.f / CDIM);
  float var = S2 * (1.f / CDIM) - mean * mean;
  float rstd = rsqrtf(var + 1e-5f);
  float4 wv4 = *(const float4*)(w + tid * 4);
  float4 bv4 = *(const float4*)(b + tid * 4);
  ushort4 o;
  o.x = f2bf((v.x - mean) * rstd * wv4.x + bv4.x);
  o.y = f2bf((v.y - mean) * rstd * wv4.y + bv4.y);
  o.z = f2bf((v.z - mean) * rstd * wv4.z + bv4.z);
  o.w = f2bf((v.w - mean) * rstd * wv4.w + bv4.w);
  *(ushort4*)(out + (size_t)row * CDIM + tid * 4) = o;
}

// ---------------- bf16 GEMM: C[M,N] = A[M,K] @ Bt[N,K]^T (+epilogue)
// BM=128, BN=256, BK=32; 8 waves (2Mx4N), per-wave 64x64 (acc[4][4]=64 VGPR).
// TWO K-tiles per barrier iteration (the R13/R14 attn win ported): ring-4 LDS
// 96KB; per iter {vmcnt(0) -> barrier -> stage tiles t+2,t+3 (into buffers
// consumed LAST iter; disjoint from this iter's reads) -> compute tiles t,t+1}.
// vmcnt(0) is safe here: waited loads were issued a full iteration (~1700cy)
// earlier >> HBM latency. Halves barrier/vmcnt events per K-tile.
// 16x16x32 MFMA with the measured-conflict-free fq-slot fragment reads.
// Slot swizzle: data(row,slot) at slot^((row>>1)&3) within 64B rows; staging
// global source pre-applies the involution (same involution; 0 conflicts).
// EPI 0: +bias -> bf16; 1: gelu(+bias) -> bf16; 3: +bias+f32resid -> bf16;
// EPI 4: +bias+bf16resid -> fp32.
template <int EPI>
__global__ __launch_bounds__(512, 2)
void k_gemm(const unsigned short* __restrict__ A,
            const unsigned short* __restrict__ Bt,
            const float* __restrict__ bias,
            const void* __restrict__ resid,
            void* __restrict__ Cout,
            int M, int N, int K) {
  constexpr int ABYTES = 128 * 64;   // 8KB
  constexpr int BBYTES = 256 * 64;   // 16KB
  constexpr int BUFSZ = ABYTES + BBYTES;  // 24KB
  __shared__ __align__(16) char lds[4 * BUFSZ];  // 96KB (ring-4)
  const int tid = threadIdx.x;
  const int wid = tid >> 6, lane = tid & 63;
  const int wm = wid >> 2, wn = wid & 3;
  const int fr = lane & 15, fq = lane >> 4;

  // XCD-aware bijective swizzle (m204) of flat block id
  const int gx = gridDim.x;
  int flat = blockIdx.y * gx + blockIdx.x;
  {
    const int nwg = gx * gridDim.y;
    int q = nwg >> 3, r = nwg & 7;
    int xcd = flat & 7, idx = flat >> 3;
    flat = (xcd < r ? xcd * (q + 1) : r * (q + 1) + (xcd - r) * q) + idx;
  }
  const int bx = flat % gx, by = flat / gx;
  const long brow = (long)by * 128, bcol = (long)bx * 256;

  // staging: lane l covers row (l>>2) of a 16-row chunk; fetches global slot
  // (l&3)^((l>>3)&3) so the linear LDS dest holds the swizzled layout.
  const int sby = (((lane & 3) ^ ((lane >> 3) & 3)) << 4);
  const char* gA = (const char*)(A + (size_t)(brow + wid * 16 + (lane >> 2)) * K) + sby;
  const char* gB = (const char*)(Bt + (size_t)(bcol + wid * 32 + (lane >> 2)) * K) + sby;

  const int NT = K >> 5;  // always even here (32 or 128)

#define STAGE_A(tt, bf)                                                 \
  ldg_lds16(lds + (bf) * BUFSZ + wid * 1024, gA + (size_t)(tt) * 64)
#define STAGE_B(tt, bf)                                                 \
  do {                                                                  \
    char* d_ = lds + (bf) * BUFSZ + ABYTES + wid * 2048;                \
    ldg_lds16(d_, gB + (size_t)(tt) * 64);                              \
    ldg_lds16(d_ + 1024, gB + (size_t)16 * K * 2 + (size_t)(tt) * 64);  \
  } while (0)

  // prologue: stage tiles 0 and 1 (3 loads/wave each)
  STAGE_A(0, 0); STAGE_B(0, 0);
  STAGE_A(1, 1); STAGE_B(1, 1);

  f32x4 acc[4][4];
  const f32x4 vzero = {0.f, 0.f, 0.f, 0.f};
#pragma unroll
  for (int m = 0; m < 4; ++m)
#pragma unroll
    for (int n = 0; n < 4; ++n) acc[m][n] = vzero;

  const int ksw = ((fq ^ ((fr >> 1) & 3)) << 4);
  for (int t = 0; t < NT; t += 2) {
    asm volatile("s_waitcnt vmcnt(0)" ::: "memory");  // tiles t,t+1 staged
    __builtin_amdgcn_s_barrier();
    __builtin_amdgcn_sched_barrier(0);
    if (t + 2 < NT) {  // stage next pair into buffers consumed last iter
      STAGE_A(t + 2, (t + 2) & 3); STAGE_B(t + 2, (t + 2) & 3);
      STAGE_A(t + 3, (t + 3) & 3); STAGE_B(t + 3, (t + 3) & 3);
    }
#pragma unroll
    for (int s = 0; s < 2; ++s) {
      const char* pA = lds + ((t + s) & 3) * BUFSZ;
      const char* pB = pA + ABYTES;
      bf16x8 af[4], bfr[4];
#pragma unroll
      for (int m = 0; m < 4; ++m)
        af[m] = *(const bf16x8*)(pA + (wm * 64 + m * 16 + fr) * 64 + ksw);
#pragma unroll
      for (int n = 0; n < 4; ++n)
        bfr[n] = *(const bf16x8*)(pB + (wn * 64 + n * 16 + fr) * 64 + ksw);
      __builtin_amdgcn_s_setprio(1);
#pragma unroll
      for (int m = 0; m < 4; ++m)
#pragma unroll
        for (int n = 0; n < 4; ++n)
          acc[m][n] = __builtin_amdgcn_mfma_f32_16x16x32_bf16(af[m], bfr[n], acc[m][n], 0, 0, 0);
      __builtin_amdgcn_s_setprio(0);
    }
    __builtin_amdgcn_sched_barrier(0);  // pin iter window (ring correctness)
  }
#undef STAGE_A
#undef STAGE_B

  // epilogue
#pragma unroll
  for (int m = 0; m < 4; ++m) {
    long row = brow + wm * 64 + m * 16 + fq * 4;
#pragma unroll
    for (int n = 0; n < 4; ++n) {
      long col = bcol + wn * 64 + n * 16 + fr;
      float bv = bias[col];
#pragma unroll
      for (int r = 0; r < 4; ++r) {
        float v = acc[m][n][r] + bv;
        long idx = (row + r) * (long)N + col;
        if (EPI == 0) {
          ((unsigned short*)Cout)[idx] = f2bf(v);
        } else if (EPI == 1) {
          ((unsigned short*)Cout)[idx] = f2bf(gelu_f(v));
        } else if (EPI == 3) {
          ((unsigned short*)Cout)[idx] = f2bf(v + ((const float*)resid)[idx]);
        } else {
          ((float*)Cout)[idx] = v + bf2f(((const unsigned short*)resid)[idx]);
        }
      }
    }
  }
}

// ---------------- build V^T: qkv bf16 [8192][3072] (v at col 2048+h*64) -> vt [b,h,64,2048]
__global__ __launch_bounds__(256) void k_build_vt(const unsigned short* __restrict__ qkv,
                                                  unsigned short* __restrict__ vt) {
  __shared__ __align__(16) unsigned short tl[64][80];
  int bh = blockIdx.x, b = bh >> 4, h = bh & 15;
  int t0 = blockIdx.y * 64;
  int tid = threadIdx.x;
  int r = tid >> 2, cb = (tid & 3) * 16;
  const unsigned short* src =
      qkv + (size_t)(b * TSEQ + t0 + r) * (3 * CDIM) + 2 * CDIM + h * HDIM + cb;
  *(uint4*)&tl[r][cb] = *(const uint4*)src;
  *(uint4*)&tl[r][cb + 8] = *(const uint4*)(src + 8);
  __syncthreads();
  int d = tid >> 2, tb = (tid & 3) * 16;
  union { unsigned short u[16]; uint4 v[2]; } o;
#pragma unroll
  for (int j = 0; j < 16; ++j) o.u[j] = tl[tb + j][d];
  unsigned short* dst = vt + ((size_t)bh * HDIM + d) * TSEQ + t0 + tb;
  *(uint4*)dst = o.v[0];
  *(uint4*)(dst + 8) = o.v[1];
}

// ---------------- flash attention (causal), swapped-QK^T 32x32, paired q-tiles,
// block-shared LDS-staged K/V, FOUR kv-tiles per barrier iteration.
struct QSt {
  f32x16 OTlo, OThi;
  float m, l;
};

__device__ __forceinline__ void attn_qk_sm_pv(
    const bf16x8& k0, const bf16x8& k1, const bf16x8& k2, const bf16x8& k3,
    const bf16x8& v0, const bf16x8& v1, const bf16x8& v2, const bf16x8& v3,
    const bf16x8& q0f, const bf16x8& q1f, const bf16x8& q2f, const bf16x8& q3f,
    QSt& S, bool diag, int lq, int hi) {
  const float SC = 0.125f * 1.44269504088896f;  // 1/sqrt(HD) * log2(e)
  f32x16 st;
#pragma unroll
  for (int r = 0; r < 16; ++r) st[r] = 0.f;
  __builtin_amdgcn_s_setprio(1);
  st = __builtin_amdgcn_mfma_f32_32x32x16_bf16(k0, q0f, st, 0, 0, 0);
  st = __builtin_amdgcn_mfma_f32_32x32x16_bf16(k1, q1f, st, 0, 0, 0);
  st = __builtin_amdgcn_mfma_f32_32x32x16_bf16(k2, q2f, st, 0, 0, 0);
  st = __builtin_amdgcn_mfma_f32_32x32x16_bf16(k3, q3f, st, 0, 0, 0);
  __builtin_amdgcn_s_setprio(0);
#pragma unroll
  for (int r = 0; r < 16; ++r) st[r] *= SC;
  if (diag) {
#pragma unroll
    for (int r = 0; r < 16; ++r) {
      int kvl = (r & 3) + 8 * (r >> 2) + 4 * hi;
      if (kvl > lq) st[r] = -1e30f;
    }
  }
  float tmax = st[0];
#pragma unroll
  for (int r = 1; r < 16; ++r) tmax = fmaxf(tmax, st[r]);
  float tm = fmaxf(tmax, __shfl_xor(tmax, 32));
  if (__any(tm > S.m + 8.f)) {  // T13 defer-max
    float mnew = fmaxf(S.m, tm);
    float alpha = __builtin_amdgcn_exp2f(S.m - mnew);
    S.m = mnew;
    S.OTlo *= alpha;
    S.OThi *= alpha;
    S.l *= alpha;
  }
  unsigned c[8];
  float rs = 0.f;
#pragma unroll
  for (int i = 0; i < 8; ++i) {
    float pa = __builtin_amdgcn_exp2f(st[2 * i] - S.m);
    float pb = __builtin_amdgcn_exp2f(st[2 * i + 1] - S.m);
    rs += pa + pb;
    c[i] = cvt_pk_bf16(pa, pb);
  }
  S.l += rs + __shfl_xor(rs, 32);
  unsigned pc[8];
#pragma unroll
  for (int i = 0; i < 8; ++i) pc[i] = __shfl_xor(c[i], 32);
  uint4 w1, w2;
  w1.x = hi ? pc[2] : c[0]; w1.y = hi ? pc[3] : c[1];
  w1.z = hi ? c[2] : pc[0]; w1.w = hi ? c[3] : pc[1];
  w2.x = hi ? pc[6] : c[4]; w2.y = hi ? pc[7] : c[5];
  w2.z = hi ? c[6] : pc[4]; w2.w = hi ? c[7] : pc[5];
  bf16x8 f1 = __builtin_bit_cast(bf16x8, w1);
  bf16x8 f2 = __builtin_bit_cast(bf16x8, w2);
  __builtin_amdgcn_s_setprio(1);
  S.OTlo = __builtin_amdgcn_mfma_f32_32x32x16_bf16(v0, f1, S.OTlo, 0, 0, 0);
  S.OTlo = __builtin_amdgcn_mfma_f32_32x32x16_bf16(v1, f2, S.OTlo, 0, 0, 0);
  S.OThi = __builtin_amdgcn_mfma_f32_32x32x16_bf16(v2, f1, S.OThi, 0, 0, 0);
  S.OThi = __builtin_amdgcn_mfma_f32_32x32x16_bf16(v3, f2, S.OThi, 0, 0, 0);
  __builtin_amdgcn_s_setprio(0);
}

// K LDS layout per tile: 32 rows x 8 chunks(16B), chunk-column-major (bank-even).
// V LDS layout per tile: 64 rows x 4 chunks(16B), chunk-column-major.
__global__ __launch_bounds__(256, 2) void k_attn(const unsigned short* __restrict__ qkv,
                                                 const unsigned short* __restrict__ vt,
                                                 unsigned short* __restrict__ y) {
  __shared__ __align__(16) unsigned short Ks[2][4][2048];  // [quad buf][tile in quad]
  __shared__ __align__(16) unsigned short Vs[2][4][2048];
  const int bh = blockIdx.x, b = bh >> 4, h = bh & 15;
  const int wv = threadIdx.x >> 6, lane = threadIdx.x & 63;
  const int by = blockIdx.y;
  const int w = by * 4 + wv;  // 0..31
  const int lq = lane & 31, hi = lane >> 5;
  const int ntL = w, ntH = 63 - w;
  const int q0L = w * 32, q0H = (63 - w) * 32;
  const int T = 64 - 4 * by;  // divisible by 4; T-1 == max ntH in block

  const unsigned short* qrowL = qkv + ((size_t)(b * TSEQ) + q0L + lq) * (3 * CDIM) + h * HDIM;
  const unsigned short* qrowH = qkv + ((size_t)(b * TSEQ) + q0H + lq) * (3 * CDIM) + h * HDIM;
  bf16x8 qL0 = *(const bf16x8*)(qrowL + 0 + hi * 8);
  bf16x8 qL1 = *(const bf16x8*)(qrowL + 16 + hi * 8);
  bf16x8 qL2 = *(const bf16x8*)(qrowL + 32 + hi * 8);
  bf16x8 qL3 = *(const bf16x8*)(qrowL + 48 + hi * 8);
  bf16x8 qH0 = *(const bf16x8*)(qrowH + 0 + hi * 8);
  bf16x8 qH1 = *(const bf16x8*)(qrowH + 16 + hi * 8);
  bf16x8 qH2 = *(const bf16x8*)(qrowH + 32 + hi * 8);
  bf16x8 qH3 = *(const bf16x8*)(qrowH + 48 + hi * 8);

  const int kr = lane & 31, kc = wv * 2 + (lane >> 5);
  const unsigned short* gK =
      qkv + ((size_t)(b * TSEQ) + kr) * (3 * CDIM) + CDIM + h * HDIM + kc * 8;
  const unsigned short* gV = vt + ((size_t)bh * HDIM + lane) * TSEQ + wv * 8;

// stage tiles tt..tt+3 into quad buffer pb (8 gload_lds/wave)
#define STAGEKV4(pb, tt)                                                        \
  do {                                                                          \
    _Pragma("unroll")                                                           \
    for (int s_ = 0; s_ < 4; ++s_) {                                            \
      ldg_lds16((char*)Ks[pb][s_] + wv * 1024,                                  \
                gK + (size_t)(tt + s_) * 32 * (3 * CDIM));                      \
      ldg_lds16((char*)Vs[pb][s_] + wv * 1024, gV + (size_t)(tt + s_) * 32);    \
    }                                                                           \
  } while (0)

  QSt SL, SH;
#pragma unroll
  for (int r = 0; r < 16; ++r) {
    SL.OTlo[r] = 0.f; SL.OThi[r] = 0.f; SH.OTlo[r] = 0.f; SH.OThi[r] = 0.f;
  }
  SL.m = -1e30f; SL.l = 0.f; SH.m = -1e30f; SH.l = 0.f;

  STAGEKV4(0, 0);
  for (int tt = 0; tt < T; tt += 4) {
    __syncthreads();  // implicit vmcnt(0): quad pb fully staged; prior reads done
    const int pb = (tt >> 2) & 1;
    if (tt + 4 < T) STAGEKV4(pb ^ 1, tt + 4);
#pragma unroll
    for (int sub = 0; sub < 4; ++sub) {
      const int t = tt + sub;
      if (t <= ntH) {
        const unsigned short* Kb = Ks[pb][sub];
        const unsigned short* Vb = Vs[pb][sub];
        bf16x8 k0 = *(const bf16x8*)(Kb + (0 + hi) * 256 + lq * 8);
        bf16x8 k1 = *(const bf16x8*)(Kb + (2 + hi) * 256 + lq * 8);
        bf16x8 k2 = *(const bf16x8*)(Kb + (4 + hi) * 256 + lq * 8);
        bf16x8 k3 = *(const bf16x8*)(Kb + (6 + hi) * 256 + lq * 8);
        bf16x8 v0 = *(const bf16x8*)(Vb + hi * 512 + lq * 8);
        bf16x8 v1 = *(const bf16x8*)(Vb + (2 + hi) * 512 + lq * 8);
        bf16x8 v2 = *(const bf16x8*)(Vb + hi * 512 + (lq + 32) * 8);
        bf16x8 v3 = *(const bf16x8*)(Vb + (2 + hi) * 512 + (lq + 32) * 8);
        attn_qk_sm_pv(k0, k1, k2, k3, v0, v1, v2, v3,
                      qH0, qH1, qH2, qH3, SH, t == ntH, lq, hi);
        if (t <= ntL)
          attn_qk_sm_pv(k0, k1, k2, k3, v0, v1, v2, v3,
                        qL0, qL1, qL2, qL3, SL, t == ntL, lq, hi);
      }
    }
  }
#undef STAGEKV4

  {
    float inv = 1.f / SH.l;
    unsigned short* yrow = y + ((size_t)(b * TSEQ) + q0H + lq) * CDIM + h * HDIM;
#pragma unroll
    for (int r = 0; r < 16; r += 2) {
      int d = (r & 3) + 8 * (r >> 2) + 4 * hi;
      unsigned lo0 = f2bf(SH.OTlo[r] * inv), lo1 = f2bf(SH.OTlo[r + 1] * inv);
      *(unsigned*)(yrow + d) = lo0 | (lo1 << 16);
      unsigned h0 = f2bf(SH.OThi[r] * inv), h1 = f2bf(SH.OThi[r + 1] * inv);
      *(unsigned*)(yrow + 32 + d) = h0 | (h1 << 16);
    }
  }
  {
    float inv = 1.f / SL.l;
    unsigned short* yrow = y + ((size_t)(b * TSEQ) + q0L + lq) * CDIM + h * HDIM;
#pragma unroll
    for (int r = 0; r < 16; r += 2) {
      int d = (r & 3) + 8 * (r >> 2) + 4 * hi;
      unsigned lo0 = f2bf(SL.OTlo[r] * inv), lo1 = f2bf(SL.OTlo[r + 1] * inv);
      *(unsigned*)(yrow + d) = lo0 | (lo1 << 16);
      unsigned h0 = f2bf(SL.OThi[r] * inv), h1 = f2bf(SL.OThi[r + 1] * inv);
      *(unsigned*)(yrow + 32 + d) = h0 | (h1 << 16);
    }
  }
}

// ---------------- launch
extern "C" void kernel_launch(void* const* d_in, const int* in_sizes, int n_in,
                              void* d_out, int out_size, void* d_ws, size_t ws_size,
                              hipStream_t stream) {
  const float* x = (const float*)d_in[0];
  const float* ln1_w = (const float*)d_in[1];
  const float* ln1_b = (const float*)d_in[2];
  const float* attn_w = (const float*)d_in[3];
  const float* attn_b = (const float*)d_in[4];
  const float* proj_w = (const float*)d_in[5];
  const float* proj_b = (const float*)d_in[6];
  const float* ln2_w = (const float*)d_in[7];
  const float* ln2_b = (const float*)d_in[8];
  const float* fc_w = (const float*)d_in[9];
  const float* fc_b = (const float*)d_in[10];
  const float* fc_proj_w = (const float*)d_in[11];
  const float* fc_proj_b = (const float*)d_in[12];

  char* ws = (char*)d_ws;
  unsigned short* wt_attn = (unsigned short*)(ws + 0);           // [3072][1024] bf16
  unsigned short* wt_proj = (unsigned short*)(ws + 6291456);     // [1024][1024]
  unsigned short* wt_fc = (unsigned short*)(ws + 8388608);       // [4096][1024]
  unsigned short* wt_fcp = (unsigned short*)(ws + 16777216);     // [1024][4096]
  unsigned short* x1 = (unsigned short*)(ws + 25165824);         // [8192][1024] bf16 residual
  unsigned short* hbuf = (unsigned short*)(ws + 58720256);       // [8192][1024] bf16
  unsigned short* ybuf = (unsigned short*)(ws + 75497472);       // [8192][1024] bf16
  unsigned short* qkvb = (unsigned short*)(ws + 92274688);       // [8192][3072] bf16
  unsigned short* vtb = (unsigned short*)(ws + 142606336);       // [64][64][2048] bf16
  unsigned short* gbuf = (unsigned short*)(ws + 92274688);       // [8192][4096] bf16 (aliases qkv+vt)

  // 1. weight transposes
  k_wtrans<<<dim3(3072 / 32, 1024 / 32), 256, 0, stream>>>(attn_w, wt_attn, 1024, 3072);
  k_wtrans<<<dim3(1024 / 32, 1024 / 32), 256, 0, stream>>>(proj_w, wt_proj, 1024, 1024);
  k_wtrans<<<dim3(4096 / 32, 1024 / 32), 256, 0, stream>>>(fc_w, wt_fc, 1024, 4096);
  k_wtrans<<<dim3(1024 / 32, 4096 / 32), 256, 0, stream>>>(fc_proj_w, wt_fcp, 4096, 1024);

  // 2. LN1 (fp32 in)
  k_ln<0><<<NROWS, 256, 0, stream>>>(x, ln1_w, ln1_b, hbuf);

  // 3. qkv = h @ attn_w + attn_b   (128x256 tiles: 12x64 = 768 blocks)
  k_gemm<0><<<dim3(3072 / 256, NROWS / 128), 512, 0, stream>>>(
      hbuf, wt_attn, attn_b, nullptr, qkvb, NROWS, 3072, 1024);

  // 4. V^T
  k_build_vt<<<dim3(64, TSEQ / 64), 256, 0, stream>>>(qkvb, vtb);

  // 5. flash attention (4 kv-tiles per barrier iteration)
  k_attn<<<dim3(64, 8), 256, 0, stream>>>(qkvb, vtb, ybuf);

  // 6. x1 = bf16(x + y @ proj_w + proj_b)   (128x256 tiles: 256 blocks)
  k_gemm<3><<<dim3(1024 / 256, NROWS / 128), 512, 0, stream>>>(
      ybuf, wt_proj, proj_b, x, x1, NROWS, 1024, 1024);

  // 7. LN2 (bf16 in)
  k_ln<1><<<NROWS, 256, 0, stream>>>(x1, ln2_w, ln2_b, hbuf);

  // 8. g = gelu(h @ fc_w + fc_b)   (128x256 tiles: 16x64 = 1024 blocks)
  k_gemm<1><<<dim3(4096 / 256, NROWS / 128), 512, 0, stream>>>(
      hbuf, wt_fc, fc_b, nullptr, gbuf, NROWS, 4096, 1024);

  // 9. out = x1 + g @ fc_proj_w + fc_proj_b   (fp32 out, bf16 resid; 256 blocks)
  k_gemm<4><<<dim3(1024 / 256, NROWS / 128), 512, 0, stream>>>(
      gbuf, wt_fcp, fc_proj_b, x1, (float*)d_out, NROWS, 1024, 4096);
}

// Round 17
// 358.437 us; speedup vs baseline: 1.0563x; 1.0563x over previous
//
#include <hip/hip_runtime.h>
#include <stdint.h>

// Problem constants (B=4, T=2048, C=1024, H=16, HD=64)
#define TSEQ 2048
#define CDIM 1024
#define NHEAD 16
#define HDIM 64
#define NROWS 8192  // B*T

typedef __bf16 bf16x8 __attribute__((ext_vector_type(8)));
typedef float f32x4 __attribute__((ext_vector_type(4)));
typedef float f32x16 __attribute__((ext_vector_type(16)));

__device__ __forceinline__ unsigned short f2bf(float f) {
  unsigned u = __builtin_bit_cast(unsigned, f);
  u = u + 0x7fffu + ((u >> 16) & 1u);
  return (unsigned short)(u >> 16);
}

__device__ __forceinline__ float bf2f(unsigned short u) {
  return __builtin_bit_cast(float, (unsigned)u << 16);
}

__device__ __forceinline__ unsigned cvt_pk_bf16(float a, float b) {
  unsigned r;
  asm("v_cvt_pk_bf16_f32 %0, %1, %2" : "=v"(r) : "v"(a), "v"(b));
  return r;
}

__device__ __forceinline__ float gelu_f(float x) {
  float x3 = x * x * x;
  float z = 0.7978845608028654f * (x + 0.044715f * x3);
  float e = __expf(2.f * z);
  float t = 1.f - 2.f / (e + 1.f);
  return 0.5f * x * (1.f + t);
}

// async 16B global->LDS (lds dest must be wave-uniform; HW adds lane*16)
__device__ __forceinline__ void ldg_lds16(void* lds, const void* gsrc) {
  __builtin_amdgcn_global_load_lds(
      (__attribute__((address_space(1))) unsigned int*)(uintptr_t)gsrc,
      (__attribute__((address_space(3))) unsigned int*)lds,
      16, 0, 0);
}

// ---------------- weight transpose+convert: W fp32 [K][N] -> Wt bf16 [N][K]
__global__ __launch_bounds__(256) void k_wtrans(const float* __restrict__ W,
                                                unsigned short* __restrict__ Wt,
                                                int K, int N) {
  __shared__ unsigned short tl[32][40];
  int n0 = blockIdx.x * 32, k0 = blockIdx.y * 32;
  int tid = threadIdx.x;
  int r = tid >> 3, c4 = (tid & 7) * 4;
  float4 v = *(const float4*)(W + (size_t)(k0 + r) * N + n0 + c4);
  ushort4 o;
  o.x = f2bf(v.x); o.y = f2bf(v.y); o.z = f2bf(v.z); o.w = f2bf(v.w);
  *(ushort4*)&tl[r][c4] = o;
  __syncthreads();
  int n = tid >> 3, k4 = (tid & 7) * 4;
  ushort4 w;
  w.x = tl[k4 + 0][n]; w.y = tl[k4 + 1][n]; w.z = tl[k4 + 2][n]; w.w = tl[k4 + 3][n];
  *(ushort4*)(Wt + (size_t)(n0 + n) * K + k0 + k4) = w;
}

// ---------------- layernorm: IN 0: fp32 input; IN 1: bf16 input -> bf16 out
template <int IN>
__global__ __launch_bounds__(256) void k_ln(const void* __restrict__ xin,
                                            const float* __restrict__ w,
                                            const float* __restrict__ b,
                                            unsigned short* __restrict__ out) {
  int row = blockIdx.x;
  int tid = threadIdx.x;
  float4 v;
  if (IN == 0) {
    v = *(const float4*)((const float*)xin + (size_t)row * CDIM + tid * 4);
  } else {
    ushort4 u = *(const ushort4*)((const unsigned short*)xin + (size_t)row * CDIM + tid * 4);
    v.x = bf2f(u.x); v.y = bf2f(u.y); v.z = bf2f(u.z); v.w = bf2f(u.w);
  }
  float s = v.x + v.y + v.z + v.w;
  float s2 = v.x * v.x + v.y * v.y + v.z * v.z + v.w * v.w;
#pragma unroll
  for (int off = 32; off; off >>= 1) {
    s += __shfl_xor(s, off);
    s2 += __shfl_xor(s2, off);
  }
  __shared__ float rbuf[8];
  int wv = tid >> 6, lane = tid & 63;
  if (lane == 0) { rbuf[wv] = s; rbuf[4 + wv] = s2; }
  __syncthreads();
  float S1 = rbuf[0] + rbuf[1] + rbuf[2] + rbuf[3];
  float S2 = rbuf[4] + rbuf[5] + rbuf[6] + rbuf[7];
  float mean = S1 * (1.f / CDIM);
  float var = S2 * (1.f / CDIM) - mean * mean;
  float rstd = rsqrtf(var + 1e-5f);
  float4 wv4 = *(const float4*)(w + tid * 4);
  float4 bv4 = *(const float4*)(b + tid * 4);
  ushort4 o;
  o.x = f2bf((v.x - mean) * rstd * wv4.x + bv4.x);
  o.y = f2bf((v.y - mean) * rstd * wv4.y + bv4.y);
  o.z = f2bf((v.z - mean) * rstd * wv4.z + bv4.z);
  o.w = f2bf((v.w - mean) * rstd * wv4.w + bv4.w);
  *(ushort4*)(out + (size_t)row * CDIM + tid * 4) = o;
}

// ---------------- bf16 GEMM (R10-exact loop): C[M,N] = A[M,K] @ Bt[N,K]^T
// BM=128, BN=256, BK=32; 8 waves (2Mx4N), per-wave 64x64 (acc[4][4]=64 VGPR).
// Ring-3 LDS 72KB -> 2 blocks/CU (dropping to 1 blk/CU costs ~18%: R7, R15);
// counted vmcnt(3); ONE barrier per K-tile; sched_barrier pins;
// 16x16x32 MFMA with the measured-conflict-free fq-slot fragment reads.
// Slot swizzle: data(row,slot) at slot^((row>>1)&3) within 64B rows; staging
// global source pre-applies the involution (same involution; 0 conflicts).
// EPI 0: +bias -> bf16; 1: gelu(+bias) -> bf16; 3: +bias+f32resid -> bf16;
// EPI 4: +bias+bf16resid -> fp32.
template <int EPI>
__global__ __launch_bounds__(512, 4)
void k_gemm(const unsigned short* __restrict__ A,
            const unsigned short* __restrict__ Bt,
            const float* __restrict__ bias,
            const void* __restrict__ resid,
            void* __restrict__ Cout,
            int M, int N, int K) {
  constexpr int ABYTES = 128 * 64;   // 8KB
  constexpr int BBYTES = 256 * 64;   // 16KB
  constexpr int BUFSZ = ABYTES + BBYTES;  // 24KB
  __shared__ __align__(16) char lds[3 * BUFSZ];  // 72KB
  const int tid = threadIdx.x;
  const int wid = tid >> 6, lane = tid & 63;
  const int wm = wid >> 2, wn = wid & 3;
  const int fr = lane & 15, fq = lane >> 4;

  // XCD-aware bijective swizzle (m204) of flat block id
  const int gx = gridDim.x;
  int flat = blockIdx.y * gx + blockIdx.x;
  {
    const int nwg = gx * gridDim.y;
    int q = nwg >> 3, r = nwg & 7;
    int xcd = flat & 7, idx = flat >> 3;
    flat = (xcd < r ? xcd * (q + 1) : r * (q + 1) + (xcd - r) * q) + idx;
  }
  const int bx = flat % gx, by = flat / gx;
  const long brow = (long)by * 128, bcol = (long)bx * 256;

  // staging: lane l covers row (l>>2) of a 16-row chunk; fetches global slot
  // (l&3)^((l>>3)&3) so the linear LDS dest holds the swizzled layout.
  const int sby = (((lane & 3) ^ ((lane >> 3) & 3)) << 4);
  const char* gA = (const char*)(A + (size_t)(brow + wid * 16 + (lane >> 2)) * K) + sby;
  const char* gB = (const char*)(Bt + (size_t)(bcol + wid * 32 + (lane >> 2)) * K) + sby;

  const int NT = K >> 5;

#define STAGE_A(tt, bf)                                                 \
  ldg_lds16(lds + (bf) * BUFSZ + wid * 1024, gA + (size_t)(tt) * 64)
#define STAGE_B(tt, bf)                                                 \
  do {                                                                  \
    char* d_ = lds + (bf) * BUFSZ + ABYTES + wid * 2048;                \
    ldg_lds16(d_, gB + (size_t)(tt) * 64);                              \
    ldg_lds16(d_ + 1024, gB + (size_t)16 * K * 2 + (size_t)(tt) * 64);  \
  } while (0)

  // prologue: stage tiles 0 and 1 (3 loads/wave each)
  STAGE_A(0, 0); STAGE_B(0, 0);
  STAGE_A(1, 1); STAGE_B(1, 1);

  f32x4 acc[4][4];
  const f32x4 vzero = {0.f, 0.f, 0.f, 0.f};
#pragma unroll
  for (int m = 0; m < 4; ++m)
#pragma unroll
    for (int n = 0; n < 4; ++n) acc[m][n] = vzero;

  const int ksw = ((fq ^ ((fr >> 1) & 3)) << 4);
  int buf = 0;
  for (int t = 0; t < NT; ++t) {
    if (t + 1 < NT) asm volatile("s_waitcnt vmcnt(3)" ::: "memory");
    else            asm volatile("s_waitcnt vmcnt(0)" ::: "memory");
    __builtin_amdgcn_s_barrier();
    __builtin_amdgcn_sched_barrier(0);
    const char* pA = lds + buf * BUFSZ;
    const char* pB = pA + ABYTES;
    int nbuf = buf + 2; if (nbuf >= 3) nbuf -= 3;
    if (t + 2 < NT) { STAGE_A(t + 2, nbuf); STAGE_B(t + 2, nbuf); }
    bf16x8 af[4], bfr[4];
#pragma unroll
    for (int m = 0; m < 4; ++m)
      af[m] = *(const bf16x8*)(pA + (wm * 64 + m * 16 + fr) * 64 + ksw);
#pragma unroll
    for (int n = 0; n < 4; ++n)
      bfr[n] = *(const bf16x8*)(pB + (wn * 64 + n * 16 + fr) * 64 + ksw);
    __builtin_amdgcn_s_setprio(1);
#pragma unroll
    for (int m = 0; m < 4; ++m)
#pragma unroll
      for (int n = 0; n < 4; ++n)
        acc[m][n] = __builtin_amdgcn_mfma_f32_16x16x32_bf16(af[m], bfr[n], acc[m][n], 0, 0, 0);
    __builtin_amdgcn_s_setprio(0);
    __builtin_amdgcn_sched_barrier(0);  // pin iter window (ring correctness)
    buf = buf + 1; if (buf == 3) buf = 0;
  }
#undef STAGE_A
#undef STAGE_B

  // epilogue
#pragma unroll
  for (int m = 0; m < 4; ++m) {
    long row = brow + wm * 64 + m * 16 + fq * 4;
#pragma unroll
    for (int n = 0; n < 4; ++n) {
      long col = bcol + wn * 64 + n * 16 + fr;
      float bv = bias[col];
#pragma unroll
      for (int r = 0; r < 4; ++r) {
        float v = acc[m][n][r] + bv;
        long idx = (row + r) * (long)N + col;
        if (EPI == 0) {
          ((unsigned short*)Cout)[idx] = f2bf(v);
        } else if (EPI == 1) {
          ((unsigned short*)Cout)[idx] = f2bf(gelu_f(v));
        } else if (EPI == 3) {
          ((unsigned short*)Cout)[idx] = f2bf(v + ((const float*)resid)[idx]);
        } else {
          ((float*)Cout)[idx] = v + bf2f(((const unsigned short*)resid)[idx]);
        }
      }
    }
  }
}

// ---------------- build V^T: qkv bf16 [8192][3072] (v at col 2048+h*64) -> vt [b,h,64,2048]
__global__ __launch_bounds__(256) void k_build_vt(const unsigned short* __restrict__ qkv,
                                                  unsigned short* __restrict__ vt) {
  __shared__ __align__(16) unsigned short tl[64][80];
  int bh = blockIdx.x, b = bh >> 4, h = bh & 15;
  int t0 = blockIdx.y * 64;
  int tid = threadIdx.x;
  int r = tid >> 2, cb = (tid & 3) * 16;
  const unsigned short* src =
      qkv + (size_t)(b * TSEQ + t0 + r) * (3 * CDIM) + 2 * CDIM + h * HDIM + cb;
  *(uint4*)&tl[r][cb] = *(const uint4*)src;
  *(uint4*)&tl[r][cb + 8] = *(const uint4*)(src + 8);
  __syncthreads();
  int d = tid >> 2, tb = (tid & 3) * 16;
  union { unsigned short u[16]; uint4 v[2]; } o;
#pragma unroll
  for (int j = 0; j < 16; ++j) o.u[j] = tl[tb + j][d];
  unsigned short* dst = vt + ((size_t)bh * HDIM + d) * TSEQ + t0 + tb;
  *(uint4*)dst = o.v[0];
  *(uint4*)(dst + 8) = o.v[1];
}

// ---------------- flash attention (causal), swapped-QK^T 32x32, paired q-tiles,
// block-shared LDS-staged K/V, FOUR kv-tiles per barrier iteration (amortizes
// the __syncthreads + vmcnt-drain + barrier-latency overhead).
struct QSt {
  f32x16 OTlo, OThi;
  float m, l;
};

__device__ __forceinline__ void attn_qk_sm_pv(
    const bf16x8& k0, const bf16x8& k1, const bf16x8& k2, const bf16x8& k3,
    const bf16x8& v0, const bf16x8& v1, const bf16x8& v2, const bf16x8& v3,
    const bf16x8& q0f, const bf16x8& q1f, const bf16x8& q2f, const bf16x8& q3f,
    QSt& S, bool diag, int lq, int hi) {
  const float SC = 0.125f * 1.44269504088896f;  // 1/sqrt(HD) * log2(e)
  f32x16 st;
#pragma unroll
  for (int r = 0; r < 16; ++r) st[r] = 0.f;
  __builtin_amdgcn_s_setprio(1);
  st = __builtin_amdgcn_mfma_f32_32x32x16_bf16(k0, q0f, st, 0, 0, 0);
  st = __builtin_amdgcn_mfma_f32_32x32x16_bf16(k1, q1f, st, 0, 0, 0);
  st = __builtin_amdgcn_mfma_f32_32x32x16_bf16(k2, q2f, st, 0, 0, 0);
  st = __builtin_amdgcn_mfma_f32_32x32x16_bf16(k3, q3f, st, 0, 0, 0);
  __builtin_amdgcn_s_setprio(0);
#pragma unroll
  for (int r = 0; r < 16; ++r) st[r] *= SC;
  if (diag) {
#pragma unroll
    for (int r = 0; r < 16; ++r) {
      int kvl = (r & 3) + 8 * (r >> 2) + 4 * hi;
      if (kvl > lq) st[r] = -1e30f;
    }
  }
  float tmax = st[0];
#pragma unroll
  for (int r = 1; r < 16; ++r) tmax = fmaxf(tmax, st[r]);
  float tm = fmaxf(tmax, __shfl_xor(tmax, 32));
  if (__any(tm > S.m + 8.f)) {  // T13 defer-max
    float mnew = fmaxf(S.m, tm);
    float alpha = __builtin_amdgcn_exp2f(S.m - mnew);
    S.m = mnew;
    S.OTlo *= alpha;
    S.OThi *= alpha;
    S.l *= alpha;
  }
  unsigned c[8];
  float rs = 0.f;
#pragma unroll
  for (int i = 0; i < 8; ++i) {
    float pa = __builtin_amdgcn_exp2f(st[2 * i] - S.m);
    float pb = __builtin_amdgcn_exp2f(st[2 * i + 1] - S.m);
    rs += pa + pb;
    c[i] = cvt_pk_bf16(pa, pb);
  }
  S.l += rs + __shfl_xor(rs, 32);
  unsigned pc[8];
#pragma unroll
  for (int i = 0; i < 8; ++i) pc[i] = __shfl_xor(c[i], 32);
  uint4 w1, w2;
  w1.x = hi ? pc[2] : c[0]; w1.y = hi ? pc[3] : c[1];
  w1.z = hi ? c[2] : pc[0]; w1.w = hi ? c[3] : pc[1];
  w2.x = hi ? pc[6] : c[4]; w2.y = hi ? pc[7] : c[5];
  w2.z = hi ? c[6] : pc[4]; w2.w = hi ? c[7] : pc[5];
  bf16x8 f1 = __builtin_bit_cast(bf16x8, w1);
  bf16x8 f2 = __builtin_bit_cast(bf16x8, w2);
  __builtin_amdgcn_s_setprio(1);
  S.OTlo = __builtin_amdgcn_mfma_f32_32x32x16_bf16(v0, f1, S.OTlo, 0, 0, 0);
  S.OTlo = __builtin_amdgcn_mfma_f32_32x32x16_bf16(v1, f2, S.OTlo, 0, 0, 0);
  S.OThi = __builtin_amdgcn_mfma_f32_32x32x16_bf16(v2, f1, S.OThi, 0, 0, 0);
  S.OThi = __builtin_amdgcn_mfma_f32_32x32x16_bf16(v3, f2, S.OThi, 0, 0, 0);
  __builtin_amdgcn_s_setprio(0);
}

// K LDS layout per tile: 32 rows x 8 chunks(16B), chunk-column-major (bank-even).
// V LDS layout per tile: 64 rows x 4 chunks(16B), chunk-column-major.
__global__ __launch_bounds__(256, 2) void k_attn(const unsigned short* __restrict__ qkv,
                                                 const unsigned short* __restrict__ vt,
                                                 unsigned short* __restrict__ y) {
  __shared__ __align__(16) unsigned short Ks[2][4][2048];  // [quad buf][tile in quad]
  __shared__ __align__(16) unsigned short Vs[2][4][2048];
  const int bh = blockIdx.x, b = bh >> 4, h = bh & 15;
  const int wv = threadIdx.x >> 6, lane = threadIdx.x & 63;
  const int by = blockIdx.y;
  const int w = by * 4 + wv;  // 0..31
  const int lq = lane & 31, hi = lane >> 5;
  const int ntL = w, ntH = 63 - w;
  const int q0L = w * 32, q0H = (63 - w) * 32;
  const int T = 64 - 4 * by;  // divisible by 4; T-1 == max ntH in block

  const unsigned short* qrowL = qkv + ((size_t)(b * TSEQ) + q0L + lq) * (3 * CDIM) + h * HDIM;
  const unsigned short* qrowH = qkv + ((size_t)(b * TSEQ) + q0H + lq) * (3 * CDIM) + h * HDIM;
  bf16x8 qL0 = *(const bf16x8*)(qrowL + 0 + hi * 8);
  bf16x8 qL1 = *(const bf16x8*)(qrowL + 16 + hi * 8);
  bf16x8 qL2 = *(const bf16x8*)(qrowL + 32 + hi * 8);
  bf16x8 qL3 = *(const bf16x8*)(qrowL + 48 + hi * 8);
  bf16x8 qH0 = *(const bf16x8*)(qrowH + 0 + hi * 8);
  bf16x8 qH1 = *(const bf16x8*)(qrowH + 16 + hi * 8);
  bf16x8 qH2 = *(const bf16x8*)(qrowH + 32 + hi * 8);
  bf16x8 qH3 = *(const bf16x8*)(qrowH + 48 + hi * 8);

  const int kr = lane & 31, kc = wv * 2 + (lane >> 5);
  const unsigned short* gK =
      qkv + ((size_t)(b * TSEQ) + kr) * (3 * CDIM) + CDIM + h * HDIM + kc * 8;
  const unsigned short* gV = vt + ((size_t)bh * HDIM + lane) * TSEQ + wv * 8;

// stage tiles tt..tt+3 into quad buffer pb (8 gload_lds/wave)
#define STAGEKV4(pb, tt)                                                        \
  do {                                                                          \
    _Pragma("unroll")                                                           \
    for (int s_ = 0; s_ < 4; ++s_) {                                            \
      ldg_lds16((char*)Ks[pb][s_] + wv * 1024,                                  \
                gK + (size_t)(tt + s_) * 32 * (3 * CDIM));                      \
      ldg_lds16((char*)Vs[pb][s_] + wv * 1024, gV + (size_t)(tt + s_) * 32);    \
    }                                                                           \
  } while (0)

  QSt SL, SH;
#pragma unroll
  for (int r = 0; r < 16; ++r) {
    SL.OTlo[r] = 0.f; SL.OThi[r] = 0.f; SH.OTlo[r] = 0.f; SH.OThi[r] = 0.f;
  }
  SL.m = -1e30f; SL.l = 0.f; SH.m = -1e30f; SH.l = 0.f;

  STAGEKV4(0, 0);
  for (int tt = 0; tt < T; tt += 4) {
    __syncthreads();  // implicit vmcnt(0): quad pb fully staged; prior reads done
    const int pb = (tt >> 2) & 1;
    if (tt + 4 < T) STAGEKV4(pb ^ 1, tt + 4);
#pragma unroll
    for (int sub = 0; sub < 4; ++sub) {
      const int t = tt + sub;
      if (t <= ntH) {
        const unsigned short* Kb = Ks[pb][sub];
        const unsigned short* Vb = Vs[pb][sub];
        bf16x8 k0 = *(const bf16x8*)(Kb + (0 + hi) * 256 + lq * 8);
        bf16x8 k1 = *(const bf16x8*)(Kb + (2 + hi) * 256 + lq * 8);
        bf16x8 k2 = *(const bf16x8*)(Kb + (4 + hi) * 256 + lq * 8);
        bf16x8 k3 = *(const bf16x8*)(Kb + (6 + hi) * 256 + lq * 8);
        bf16x8 v0 = *(const bf16x8*)(Vb + hi * 512 + lq * 8);
        bf16x8 v1 = *(const bf16x8*)(Vb + (2 + hi) * 512 + lq * 8);
        bf16x8 v2 = *(const bf16x8*)(Vb + hi * 512 + (lq + 32) * 8);
        bf16x8 v3 = *(const bf16x8*)(Vb + (2 + hi) * 512 + (lq + 32) * 8);
        attn_qk_sm_pv(k0, k1, k2, k3, v0, v1, v2, v3,
                      qH0, qH1, qH2, qH3, SH, t == ntH, lq, hi);
        if (t <= ntL)
          attn_qk_sm_pv(k0, k1, k2, k3, v0, v1, v2, v3,
                        qL0, qL1, qL2, qL3, SL, t == ntL, lq, hi);
      }
    }
  }
#undef STAGEKV4

  {
    float inv = 1.f / SH.l;
    unsigned short* yrow = y + ((size_t)(b * TSEQ) + q0H + lq) * CDIM + h * HDIM;
#pragma unroll
    for (int r = 0; r < 16; r += 2) {
      int d = (r & 3) + 8 * (r >> 2) + 4 * hi;
      unsigned lo0 = f2bf(SH.OTlo[r] * inv), lo1 = f2bf(SH.OTlo[r + 1] * inv);
      *(unsigned*)(yrow + d) = lo0 | (lo1 << 16);
      unsigned h0 = f2bf(SH.OThi[r] * inv), h1 = f2bf(SH.OThi[r + 1] * inv);
      *(unsigned*)(yrow + 32 + d) = h0 | (h1 << 16);
    }
  }
  {
    float inv = 1.f / SL.l;
    unsigned short* yrow = y + ((size_t)(b * TSEQ) + q0L + lq) * CDIM + h * HDIM;
#pragma unroll
    for (int r = 0; r < 16; r += 2) {
      int d = (r & 3) + 8 * (r >> 2) + 4 * hi;
      unsigned lo0 = f2bf(SL.OTlo[r] * inv), lo1 = f2bf(SL.OTlo[r + 1] * inv);
      *(unsigned*)(yrow + d) = lo0 | (lo1 << 16);
      unsigned h0 = f2bf(SL.OThi[r] * inv), h1 = f2bf(SL.OThi[r + 1] * inv);
      *(unsigned*)(yrow + 32 + d) = h0 | (h1 << 16);
    }
  }
}

// ---------------- launch
extern "C" void kernel_launch(void* const* d_in, const int* in_sizes, int n_in,
                              void* d_out, int out_size, void* d_ws, size_t ws_size,
                              hipStream_t stream) {
  const float* x = (const float*)d_in[0];
  const float* ln1_w = (const float*)d_in[1];
  const float* ln1_b = (const float*)d_in[2];
  const float* attn_w = (const float*)d_in[3];
  const float* attn_b = (const float*)d_in[4];
  const float* proj_w = (const float*)d_in[5];
  const float* proj_b = (const float*)d_in[6];
  const float* ln2_w = (const float*)d_in[7];
  const float* ln2_b = (const float*)d_in[8];
  const float* fc_w = (const float*)d_in[9];
  const float* fc_b = (const float*)d_in[10];
  const float* fc_proj_w = (const float*)d_in[11];
  const float* fc_proj_b = (const float*)d_in[12];

  char* ws = (char*)d_ws;
  unsigned short* wt_attn = (unsigned short*)(ws + 0);           // [3072][1024] bf16
  unsigned short* wt_proj = (unsigned short*)(ws + 6291456);     // [1024][1024]
  unsigned short* wt_fc = (unsigned short*)(ws + 8388608);       // [4096][1024]
  unsigned short* wt_fcp = (unsigned short*)(ws + 16777216);     // [1024][4096]
  unsigned short* x1 = (unsigned short*)(ws + 25165824);         // [8192][1024] bf16 residual
  unsigned short* hbuf = (unsigned short*)(ws + 58720256);       // [8192][1024] bf16
  unsigned short* ybuf = (unsigned short*)(ws + 75497472);       // [8192][1024] bf16
  unsigned short* qkvb = (unsigned short*)(ws + 92274688);       // [8192][3072] bf16
  unsigned short* vtb = (unsigned short*)(ws + 142606336);       // [64][64][2048] bf16
  unsigned short* gbuf = (unsigned short*)(ws + 92274688);       // [8192][4096] bf16 (aliases qkv+vt)

  // 1. weight transposes
  k_wtrans<<<dim3(3072 / 32, 1024 / 32), 256, 0, stream>>>(attn_w, wt_attn, 1024, 3072);
  k_wtrans<<<dim3(1024 / 32, 1024 / 32), 256, 0, stream>>>(proj_w, wt_proj, 1024, 1024);
  k_wtrans<<<dim3(4096 / 32, 1024 / 32), 256, 0, stream>>>(fc_w, wt_fc, 1024, 4096);
  k_wtrans<<<dim3(1024 / 32, 4096 / 32), 256, 0, stream>>>(fc_proj_w, wt_fcp, 4096, 1024);

  // 2. LN1 (fp32 in)
  k_ln<0><<<NROWS, 256, 0, stream>>>(x, ln1_w, ln1_b, hbuf);

  // 3. qkv = h @ attn_w + attn_b   (128x256 tiles: 12x64 = 768 blocks)
  k_gemm<0><<<dim3(3072 / 256, NROWS / 128), 512, 0, stream>>>(
      hbuf, wt_attn, attn_b, nullptr, qkvb, NROWS, 3072, 1024);

  // 4. V^T
  k_build_vt<<<dim3(64, TSEQ / 64), 256, 0, stream>>>(qkvb, vtb);

  // 5. flash attention (4 kv-tiles per barrier iteration)
  k_attn<<<dim3(64, 8), 256, 0, stream>>>(qkvb, vtb, ybuf);

  // 6. x1 = bf16(x + y @ proj_w + proj_b)   (128x256 tiles: 256 blocks)
  k_gemm<3><<<dim3(1024 / 256, NROWS / 128), 512, 0, stream>>>(
      ybuf, wt_proj, proj_b, x, x1, NROWS, 1024, 1024);

  // 7. LN2 (bf16 in)
  k_ln<1><<<NROWS, 256, 0, stream>>>(x1, ln2_w, ln2_b, hbuf);

  // 8. g = gelu(h @ fc_w + fc_b)   (128x256 tiles: 16x64 = 1024 blocks)
  k_gemm<1><<<dim3(4096 / 256, NROWS / 128), 512, 0, stream>>>(
      hbuf, wt_fc, fc_b, nullptr, gbuf, NROWS, 4096, 1024);

  // 9. out = x1 + g @ fc_proj_w + fc_proj_b   (fp32 out, bf16 resid; 256 blocks)
  k_gemm<4><<<dim3(1024 / 256, NROWS / 128), 512, 0, stream>>>(
      gbuf, wt_fcp, fc_proj_b, x1, (float*)d_out, NROWS, 1024, 4096);
}